// Round 1
// baseline (2015.799 us; speedup 1.0000x reference)
//
#include <hip/hip_runtime.h>

#define T_STEPS 1024
#define BATCH 2048
#define UNITS 64
#define BTILE 4

__device__ __forceinline__ float rl(float v, int lane) {
    return __int_as_float(__builtin_amdgcn_readlane(__float_as_int(v), lane));
}

__device__ __forceinline__ float fast_rcp(float x) {
#if __has_builtin(__builtin_amdgcn_rcpf)
    return __builtin_amdgcn_rcpf(x);
#else
    return 1.0f / x;
#endif
}

__device__ __forceinline__ float fast_exp2(float x) {
#if __has_builtin(__builtin_amdgcn_exp2f)
    return __builtin_amdgcn_exp2f(x);
#else
    return exp2f(x);
#endif
}

// sigmoid(x) = 1 / (1 + 2^(-x*log2(e)))
__device__ __forceinline__ float sigf(float x) {
    return fast_rcp(1.0f + fast_exp2(-1.44269504f * x));
}

// tanh(x) = 1 - 2/(e^{2x}+1) = 1 - 2/(2^{2x*log2(e)}+1)
__device__ __forceinline__ float tanh_fast(float x) {
    float e = fast_exp2(2.88539008f * x);
    return 1.0f - 2.0f * fast_rcp(e + 1.0f);
}

// one DPP-shifted add step: x += dpp_shift(x)
__device__ __forceinline__ float dpp_add(float x, int ctrl, int row_mask) {
    int xi = __float_as_int(x);
    int sh;
    switch (ctrl) {  // ctrl must be a literal at each call site after inlining
    case 0x111: sh = __builtin_amdgcn_update_dpp(0, xi, 0x111, 0xf, 0xf, true); break; // row_shr:1
    case 0x112: sh = __builtin_amdgcn_update_dpp(0, xi, 0x112, 0xf, 0xf, true); break; // row_shr:2
    case 0x114: sh = __builtin_amdgcn_update_dpp(0, xi, 0x114, 0xf, 0xf, true); break; // row_shr:4
    case 0x118: sh = __builtin_amdgcn_update_dpp(0, xi, 0x118, 0xf, 0xf, true); break; // row_shr:8
    case 0x142: sh = __builtin_amdgcn_update_dpp(0, xi, 0x142, 0xa, 0xf, true); break; // row_bcast:15 -> rows 1,3
    default:    sh = __builtin_amdgcn_update_dpp(0, xi, 0x143, 0xc, 0xf, true); break; // row_bcast:31 -> rows 2,3
    }
    (void)row_mask;
    return x + __int_as_float(sh);
}

// full-wave (64-lane) sum, returned as a wave-uniform scalar
__device__ __forceinline__ float wave_allsum(float x) {
    x = dpp_add(x, 0x111, 0xf);
    x = dpp_add(x, 0x112, 0xf);
    x = dpp_add(x, 0x114, 0xf);
    x = dpp_add(x, 0x118, 0xf);   // lane 15 of each row-of-16 = row sum
    x = dpp_add(x, 0x142, 0xa);   // lane 31 = sum(0..31), lane 63 = sum(32..63)
    x = dpp_add(x, 0x143, 0xc);   // lane 63 = total
    return rl(x, 63);
}

// Block: 256 threads = 4 waves. Wave w owns K-chunk [16w,16w+16) of the
// 256x64 hidden matvec; lane l owns all 4 gate rows {l,64+l,128+l,192+l}
// of that chunk (weights in 64 VGPRs). BTILE=4 batch elements per block;
// wave w also does activation + layer-2 for batch b==w.
__global__ __launch_bounds__(256, 2)
void lstm_fused_kernel(const float* __restrict__ input,
                       const float* __restrict__ W_ih0,
                       const float* __restrict__ W_hh0,
                       const float* __restrict__ b_ih0,
                       const float* __restrict__ b_hh0,
                       const float* __restrict__ W_ih1,
                       const float* __restrict__ W_hh1,
                       const float* __restrict__ b_ih1,
                       const float* __restrict__ b_hh1,
                       float* __restrict__ out)
{
    const int tid = threadIdx.x;
    const int w = tid >> 6;     // wave id = K-chunk id = "my" batch for act/L2
    const int l = tid & 63;     // lane = hidden unit
    const int bbase = blockIdx.x * BTILE;

    // P[b][l][w*4+g]: K-chunk partial sums; stride 20 floats keeps the
    // float4 slots 16B-aligned (80B row) and spreads banks.
    __shared__ __align__(16) float P[BTILE][UNITS][20];
    __shared__ float hbuf[BTILE][UNITS];

    // ---- preload weights into registers ----
    // wk[g][j] = W_hh0[g*64+l][16w+j]
    float wk[4][16];
    #pragma unroll
    for (int g = 0; g < 4; ++g) {
        const float* rowp = W_hh0 + (size_t)(g * 64 + l) * 64 + (w << 4);
        #pragma unroll
        for (int j4 = 0; j4 < 4; ++j4) {
            float4 v = reinterpret_cast<const float4*>(rowp)[j4];
            wk[g][j4 * 4 + 0] = v.x;
            wk[g][j4 * 4 + 1] = v.y;
            wk[g][j4 * 4 + 2] = v.z;
            wk[g][j4 * 4 + 3] = v.w;
        }
    }
    // bias + input weight (only wave 0 applies these, once per row)
    float wih0g[4], bias0g[4];
    #pragma unroll
    for (int g = 0; g < 4; ++g) {
        int r = g * 64 + l;
        wih0g[g] = W_ih0[r];
        bias0g[g] = b_ih0[r] + b_hh0[r];
    }
    // layer-2 weights: w1[g] per-lane column, rest wave-uniform
    float w1[4], whh1[4], b1s[4];
    #pragma unroll
    for (int g = 0; g < 4; ++g) {
        w1[g] = W_ih1[g * 64 + l];
        whh1[g] = W_hh1[g];
        b1s[g] = b_ih1[g] + b_hh1[g];
    }

    // ---- state ----
    float hreg[BTILE];          // h0[b][l] replicated per wave
    #pragma unroll
    for (int b = 0; b < BTILE; ++b) hreg[b] = 0.0f;
    float c0 = 0.0f;            // c0[b==w][l]
    float h1 = 0.0f, c1 = 0.0f; // layer-2 state for b==w (wave-uniform)

    float* outrow = out + (size_t)(bbase + w) * T_STEPS;
    float xbuf[BTILE];
    #pragma unroll
    for (int b = 0; b < BTILE; ++b) xbuf[b] = 0.0f;

    #pragma unroll 1
    for (int t = 0; t < T_STEPS; ++t) {
        // refill 64 timesteps of x (only wave 0 consumes x)
        if (w == 0 && (t & 63) == 0) {
            #pragma unroll
            for (int b = 0; b < BTILE; ++b)
                xbuf[b] = input[(size_t)(bbase + b) * T_STEPS + t + l];
        }

        // ---- layer-1 matvec partials (my K-chunk) ----
        float acc[4][BTILE];    // [gate][batch]
        if (w == 0) {
            const int ti = t & 63;
            #pragma unroll
            for (int b = 0; b < BTILE; ++b) {
                float xb = rl(xbuf[b], ti);
                #pragma unroll
                for (int g = 0; g < 4; ++g)
                    acc[g][b] = fmaf(xb, wih0g[g], bias0g[g]);
            }
        } else {
            #pragma unroll
            for (int b = 0; b < BTILE; ++b)
                #pragma unroll
                for (int g = 0; g < 4; ++g) acc[g][b] = 0.0f;
        }
        #pragma unroll
        for (int j = 0; j < 16; ++j) {
            const int k = (w << 4) + j;     // wave-uniform lane index
            #pragma unroll
            for (int b = 0; b < BTILE; ++b) {
                float hk = rl(hreg[b], k);  // h0[b][k] broadcast
                #pragma unroll
                for (int g = 0; g < 4; ++g)
                    acc[g][b] = fmaf(hk, wk[g][j], acc[g][b]);
            }
        }
        // publish partials: P[b][l][w*4 + g]
        #pragma unroll
        for (int b = 0; b < BTILE; ++b) {
            float4 v = make_float4(acc[0][b], acc[1][b], acc[2][b], acc[3][b]);
            *reinterpret_cast<float4*>(&P[b][l][w << 2]) = v;
        }
        __syncthreads();

        // ---- activation for batch b == w ----
        const float4 p0 = *reinterpret_cast<const float4*>(&P[w][l][0]);
        const float4 p1 = *reinterpret_cast<const float4*>(&P[w][l][4]);
        const float4 p2 = *reinterpret_cast<const float4*>(&P[w][l][8]);
        const float4 p3 = *reinterpret_cast<const float4*>(&P[w][l][12]);
        float gi = p0.x + p1.x + p2.x + p3.x;
        float gf = p0.y + p1.y + p2.y + p3.y;
        float gg = p0.z + p1.z + p2.z + p3.z;
        float go = p0.w + p1.w + p2.w + p3.w;

        float c0n = sigf(gf) * c0 + sigf(gi) * tanh_fast(gg);
        c0 = c0n;
        float h0n = sigf(go) * tanh_fast(c0n);
        hbuf[w][l] = h0n;

        // ---- layer-2 cell for batch b == w (input = c0n, PyTorch i,f,g,o) ----
        float s0 = wave_allsum(w1[0] * c0n);
        float s1 = wave_allsum(w1[1] * c0n);
        float s2 = wave_allsum(w1[2] * c0n);
        float s3 = wave_allsum(w1[3] * c0n);
        float g1i = s0 + b1s[0] + h1 * whh1[0];
        float g1f = s1 + b1s[1] + h1 * whh1[1];
        float g1g = s2 + b1s[2] + h1 * whh1[2];
        float g1o = s3 + b1s[3] + h1 * whh1[3];
        float c1n = sigf(g1f) * c1 + sigf(g1i) * tanh_fast(g1g);
        float h1n = sigf(g1o) * tanh_fast(c1n);
        c1 = c1n;
        h1 = h1n;
        if (l == 0) outrow[t] = c1n;   // output = layer-2 cell state

        __syncthreads();
        // fetch new h0 for next step (all waves need all BTILE rows)
        #pragma unroll
        for (int b = 0; b < BTILE; ++b) hreg[b] = hbuf[b][l];
    }
}

extern "C" void kernel_launch(void* const* d_in, const int* in_sizes, int n_in,
                              void* d_out, int out_size, void* d_ws, size_t ws_size,
                              hipStream_t stream) {
    const float* input = (const float*)d_in[0];
    const float* W_ih0 = (const float*)d_in[1];
    const float* W_hh0 = (const float*)d_in[2];
    const float* b_ih0 = (const float*)d_in[3];
    const float* b_hh0 = (const float*)d_in[4];
    const float* W_ih1 = (const float*)d_in[5];
    const float* W_hh1 = (const float*)d_in[6];
    const float* b_ih1 = (const float*)d_in[7];
    const float* b_hh1 = (const float*)d_in[8];
    float* out = (float*)d_out;

    dim3 grid(BATCH / BTILE);   // 512 blocks
    dim3 block(256);
    lstm_fused_kernel<<<grid, block, 0, stream>>>(
        input, W_ih0, W_hh0, b_ih0, b_hh0, W_ih1, W_hh1, b_ih1, b_hh1, out);
}

// Round 2
// 1019.763 us; speedup vs baseline: 1.9767x; 1.9767x over previous
//
#include <hip/hip_runtime.h>

#define T_STEPS 1024
#define BATCH 2048
#define BTILE 4

typedef short short8 __attribute__((ext_vector_type(8)));
typedef float f32x4 __attribute__((ext_vector_type(4)));

__device__ __forceinline__ float rl(float v, int lane) {
    return __int_as_float(__builtin_amdgcn_readlane(__float_as_int(v), lane));
}

__device__ __forceinline__ float fast_rcp(float x) {
#if __has_builtin(__builtin_amdgcn_rcpf)
    return __builtin_amdgcn_rcpf(x);
#else
    return 1.0f / x;
#endif
}

__device__ __forceinline__ float fast_exp2(float x) {
#if __has_builtin(__builtin_amdgcn_exp2f)
    return __builtin_amdgcn_exp2f(x);
#else
    return exp2f(x);
#endif
}

// sigmoid(x) = 1 / (1 + 2^(-x*log2(e)))
__device__ __forceinline__ float sigf(float x) {
    return fast_rcp(1.0f + fast_exp2(-1.44269504f * x));
}

// tanh(x) = 1 - 2/(2^(2x*log2(e)) + 1)
__device__ __forceinline__ float tanh_fast(float x) {
    float e = fast_exp2(2.88539008f * x);
    return 1.0f - 2.0f * fast_rcp(e + 1.0f);
}

// float -> bf16 (round-to-nearest-even), as raw ushort bits
__device__ __forceinline__ unsigned short f2bf(float x) {
    unsigned u = __float_as_uint(x);
    unsigned r = u + 0x7FFFu + ((u >> 16) & 1u);
    return (unsigned short)(r >> 16);
}

__device__ __forceinline__ float dpp_add(float x, int which) {
    int xi = __float_as_int(x);
    int sh;
    switch (which) {
    case 0: sh = __builtin_amdgcn_update_dpp(0, xi, 0x111, 0xf, 0xf, true); break; // row_shr:1
    case 1: sh = __builtin_amdgcn_update_dpp(0, xi, 0x112, 0xf, 0xf, true); break; // row_shr:2
    case 2: sh = __builtin_amdgcn_update_dpp(0, xi, 0x114, 0xf, 0xf, true); break; // row_shr:4
    case 3: sh = __builtin_amdgcn_update_dpp(0, xi, 0x118, 0xf, 0xf, true); break; // row_shr:8
    case 4: sh = __builtin_amdgcn_update_dpp(0, xi, 0x142, 0xa, 0xf, true); break; // row_bcast:15
    default: sh = __builtin_amdgcn_update_dpp(0, xi, 0x143, 0xc, 0xf, true); break; // row_bcast:31
    }
    return x + __int_as_float(sh);
}

// full 64-lane sum, wave-uniform result
__device__ __forceinline__ float wave_allsum(float x) {
    x = dpp_add(x, 0);
    x = dpp_add(x, 1);
    x = dpp_add(x, 2);
    x = dpp_add(x, 3);
    x = dpp_add(x, 4);
    x = dpp_add(x, 5);
    return rl(x, 63);
}

// Per block: BTILE=4 batch rows. Layer-1 gates via MFMA:
//   D(256x16) = W_hh0(256x64)_bf16 . h^T(64x16)_bf16   (only 4 of 16 N-cols used)
// A-fragments (W) persist in registers: wave w owns M-tiles 4w..4w+3 (rows 64w..64w+63).
// h round-trips LDS as bf16 in exact B-fragment layout; batch cols 4..15 stay zero.
// Wave w does activation + layer-2 for batch b == w (thread (w,l) owns cell (b=w, u=l)).
__global__ __launch_bounds__(256, 2)
void lstm_mfma_kernel(const float* __restrict__ input,
                      const float* __restrict__ W_ih0,
                      const float* __restrict__ W_hh0,
                      const float* __restrict__ b_ih0,
                      const float* __restrict__ b_hh0,
                      const float* __restrict__ W_ih1,
                      const float* __restrict__ W_hh1,
                      const float* __restrict__ b_ih1,
                      const float* __restrict__ b_hh1,
                      float* __restrict__ out)
{
    const int tid = threadIdx.x;
    const int w = tid >> 6;      // wave id = batch within tile
    const int l = tid & 63;      // lane = hidden unit for activation phase
    const int quad = l >> 4;
    const int n16 = l & 15;
    const int bbase = blockIdx.x * BTILE;

    // B-operand staging: bufB[ktile][lane][j] = B[k=8*quad+j + 32*kt][n=lane&15]
    __shared__ __align__(16) unsigned short bufB[2][64][8];   // 2 KB
    // Gate matrix, transposed: G[n][m] (n=batch col, m=gate row), padded row
    __shared__ __align__(16) float G[16][272];                // ~17 KB

    // zero bufB once (cols n>=4 stay zero forever -> those MFMA lanes compute 0)
    reinterpret_cast<unsigned long long*>(bufB)[tid] = 0ull;

    // ---- persistent A fragments: afrag[i][kt] = W_hh0 tile (4w+i, kt) ----
    short8 afrag[4][2];
    #pragma unroll
    for (int i = 0; i < 4; ++i) {
        const int row = 16 * (4 * w + i) + n16;       // A[m][k]: m = lane&15
        #pragma unroll
        for (int kt = 0; kt < 2; ++kt) {
            const float* p = W_hh0 + (size_t)row * 64 + kt * 32 + quad * 8;
            short8 a;
            #pragma unroll
            for (int j = 0; j < 8; ++j) a[j] = (short)f2bf(p[j]);
            afrag[i][kt] = a;
        }
    }

    // per-thread activation constants for cell (b=w, u=l)
    float wih0g[4], bias0g[4];
    #pragma unroll
    for (int g = 0; g < 4; ++g) {
        int r = g * 64 + l;
        wih0g[g] = W_ih0[r];
        bias0g[g] = b_ih0[r] + b_hh0[r];
    }
    // layer-2 constants
    float w1[4], whh1[4], b1s[4];
    #pragma unroll
    for (int g = 0; g < 4; ++g) {
        w1[g] = W_ih1[g * 64 + l];
        whh1[g] = W_hh1[g];
        b1s[g] = b_ih1[g] + b_hh1[g];
    }

    float c0 = 0.0f, h1 = 0.0f, c1 = 0.0f, xbuf = 0.0f;
    const float* inrow = input + (size_t)(bbase + w) * T_STEPS;
    float* outrow = out + (size_t)(bbase + w) * T_STEPS;

    __syncthreads();

    #pragma unroll 1
    for (int t = 0; t < T_STEPS; ++t) {
        if ((t & 63) == 0) xbuf = inrow[t + l];   // refill 64 steps of x

        // ---- MFMA phase: gates(t) from h(t-1) ----
        short8 bfrag0 = *reinterpret_cast<const short8*>(&bufB[0][l][0]);
        short8 bfrag1 = *reinterpret_cast<const short8*>(&bufB[1][l][0]);
        #pragma unroll
        for (int i = 0; i < 4; ++i) {
            f32x4 z = {0.0f, 0.0f, 0.0f, 0.0f};
            z = __builtin_amdgcn_mfma_f32_16x16x32_bf16(afrag[i][0], bfrag0, z, 0, 0, 0);
            z = __builtin_amdgcn_mfma_f32_16x16x32_bf16(afrag[i][1], bfrag1, z, 0, 0, 0);
            // C layout: col n = lane&15, row m = m0 + 4*quad + reg -> contiguous in G[n][.]
            const int m0 = 16 * (4 * w + i) + 4 * quad;
            *reinterpret_cast<f32x4*>(&G[n16][m0]) = z;
        }
        __syncthreads();

        // ---- activation for cell (b=w, u=l) ----
        const float x = rl(xbuf, t & 63);
        float gi = G[w][l]       + fmaf(x, wih0g[0], bias0g[0]);
        float gf = G[w][64 + l]  + fmaf(x, wih0g[1], bias0g[1]);
        float gg = G[w][128 + l] + fmaf(x, wih0g[2], bias0g[2]);
        float go = G[w][192 + l] + fmaf(x, wih0g[3], bias0g[3]);

        float c0n = sigf(gf) * c0 + sigf(gi) * tanh_fast(gg);
        c0 = c0n;
        float h0n = sigf(go) * tanh_fast(c0n);

        // scatter h0n (bf16) into B-fragment layout for next step:
        // u=l: kt=l>>5, lane'= w + 16*((l>>3)&3), j'= l&7  =>  B[k=l][n=w]
        bufB[l >> 5][w + 16 * ((l >> 3) & 3)][l & 7] = f2bf(h0n);

        // ---- layer-2 cell (input = c0n), gates i,f,g,o ----
        float s0 = wave_allsum(w1[0] * c0n);
        float s1 = wave_allsum(w1[1] * c0n);
        float s2 = wave_allsum(w1[2] * c0n);
        float s3 = wave_allsum(w1[3] * c0n);
        float g1i = s0 + b1s[0] + h1 * whh1[0];
        float g1f = s1 + b1s[1] + h1 * whh1[1];
        float g1g = s2 + b1s[2] + h1 * whh1[2];
        float g1o = s3 + b1s[3] + h1 * whh1[3];
        float c1n = sigf(g1f) * c1 + sigf(g1i) * tanh_fast(g1g);
        float h1n = sigf(g1o) * tanh_fast(c1n);
        c1 = c1n;
        h1 = h1n;
        if (l == 0) outrow[t] = c1n;   // output = layer-2 cell state

        __syncthreads();   // bufB writes visible before next MFMA reads
    }
}

extern "C" void kernel_launch(void* const* d_in, const int* in_sizes, int n_in,
                              void* d_out, int out_size, void* d_ws, size_t ws_size,
                              hipStream_t stream) {
    const float* input = (const float*)d_in[0];
    const float* W_ih0 = (const float*)d_in[1];
    const float* W_hh0 = (const float*)d_in[2];
    const float* b_ih0 = (const float*)d_in[3];
    const float* b_hh0 = (const float*)d_in[4];
    const float* W_ih1 = (const float*)d_in[5];
    const float* W_hh1 = (const float*)d_in[6];
    const float* b_ih1 = (const float*)d_in[7];
    const float* b_hh1 = (const float*)d_in[8];
    float* out = (float*)d_out;

    dim3 grid(BATCH / BTILE);   // 512 blocks -> 2 blocks/CU
    dim3 block(256);
    lstm_mfma_kernel<<<grid, block, 0, stream>>>(
        input, W_ih0, W_hh0, b_ih0, b_hh0, W_ih1, W_hh1, b_ih1, b_hh1, out);
}

// Round 3
// 879.353 us; speedup vs baseline: 2.2924x; 1.1597x over previous
//
#include <hip/hip_runtime.h>

#define T_STEPS 1024
#define BATCH 2048
#define BTILE 4
#define GS 260   // G row stride (floats); 260 % 32 == 4 -> conflict-free b128 writes
#define HS 36    // h row stride (u32 words); 36 % 32 == 4 -> conflict-free b128 reads

typedef short short8 __attribute__((ext_vector_type(8)));
typedef float f32x4 __attribute__((ext_vector_type(4)));

__device__ __forceinline__ float rl(float v, int lane) {
    return __int_as_float(__builtin_amdgcn_readlane(__float_as_int(v), lane));
}

__device__ __forceinline__ float fast_rcp(float x) {
#if __has_builtin(__builtin_amdgcn_rcpf)
    return __builtin_amdgcn_rcpf(x);
#else
    return 1.0f / x;
#endif
}

__device__ __forceinline__ float fast_exp2(float x) {
#if __has_builtin(__builtin_amdgcn_exp2f)
    return __builtin_amdgcn_exp2f(x);
#else
    return exp2f(x);
#endif
}

__device__ __forceinline__ float sigf(float x) {
    return fast_rcp(1.0f + fast_exp2(-1.44269504f * x));
}

__device__ __forceinline__ float tanh_fast(float x) {
    float e = fast_exp2(2.88539008f * x);
    return 1.0f - 2.0f * fast_rcp(e + 1.0f);
}

// float -> bf16 bits (round-to-nearest-even)
__device__ __forceinline__ unsigned f2bf(float x) {
    unsigned u = __float_as_uint(x);
    unsigned r = u + 0x7FFFu + ((u >> 16) & 1u);
    return r >> 16;
}

__device__ __forceinline__ float dpp_add(float x, int which) {
    int xi = __float_as_int(x);
    int sh;
    switch (which) {
    case 0: sh = __builtin_amdgcn_update_dpp(0, xi, 0x111, 0xf, 0xf, true); break; // row_shr:1
    case 1: sh = __builtin_amdgcn_update_dpp(0, xi, 0x112, 0xf, 0xf, true); break; // row_shr:2
    case 2: sh = __builtin_amdgcn_update_dpp(0, xi, 0x114, 0xf, 0xf, true); break; // row_shr:4
    case 3: sh = __builtin_amdgcn_update_dpp(0, xi, 0x118, 0xf, 0xf, true); break; // row_shr:8
    case 4: sh = __builtin_amdgcn_update_dpp(0, xi, 0x142, 0xa, 0xf, true); break; // row_bcast:15
    default: sh = __builtin_amdgcn_update_dpp(0, xi, 0x143, 0xc, 0xf, true); break; // row_bcast:31
    }
    return x + __int_as_float(sh);
}

__device__ __forceinline__ float wave_allsum(float x) {
    x = dpp_add(x, 0);
    x = dpp_add(x, 1);
    x = dpp_add(x, 2);
    x = dpp_add(x, 3);
    x = dpp_add(x, 4);
    x = dpp_add(x, 5);
    return rl(x, 63);
}

// lane l receives lane l+1's value (within row of 16); only even lanes use it
__device__ __forceinline__ unsigned dpp_shl1(unsigned x) {
    return (unsigned)__builtin_amdgcn_update_dpp(0, (int)x, 0x101, 0xf, 0xf, true);
}

// Layer-1 gates via MFMA: D(256x16) = W_hh0(256x64)_bf16 . h^T(64x16)_bf16.
// Wave w holds M-tiles 4w..4w+3 of W as persistent A-fragments. h lives in LDS
// as bf16 PAIRS (u32) at row stride 36 words -> the next step's B-fragments are
// two conflict-free ds_read_b128 in exact operand order. G stored at row stride
// 260 floats (=4 mod 32) -> conflict-free f32x4 writes, 2-way (free) b32 reads.
// Layer-2 cell for step t-1 runs in the MFMA shadow of step t.
__global__ __launch_bounds__(256, 2)
void lstm_mfma2_kernel(const float* __restrict__ input,
                       const float* __restrict__ W_ih0,
                       const float* __restrict__ W_hh0,
                       const float* __restrict__ b_ih0,
                       const float* __restrict__ b_hh0,
                       const float* __restrict__ W_ih1,
                       const float* __restrict__ W_hh1,
                       const float* __restrict__ b_ih1,
                       const float* __restrict__ b_hh1,
                       float* __restrict__ out)
{
    const int tid = threadIdx.x;
    const int w = tid >> 6;      // wave id = batch within tile
    const int l = tid & 63;      // lane
    const int quad = l >> 4;
    const int n16 = l & 15;
    const int bbase = blockIdx.x * BTILE;

    __shared__ __align__(16) float G[16][GS];          // ~16.6 KB
    __shared__ __align__(16) unsigned Hb[16][HS];      // ~2.3 KB (bf16 pairs)

    // zero Hb once: rows 4..15 stay zero forever (garbage batch cols read 0)
    #pragma unroll
    for (int idx = tid; idx < 16 * HS; idx += 256)
        reinterpret_cast<unsigned*>(Hb)[idx] = 0u;

    // ---- persistent A fragments: afrag[i][kt] = W_hh0 tile (4w+i, kt) ----
    short8 afrag[4][2];
    #pragma unroll
    for (int i = 0; i < 4; ++i) {
        const int row = 16 * (4 * w + i) + n16;        // A[m][k]: m = lane&15
        #pragma unroll
        for (int kt = 0; kt < 2; ++kt) {
            const float* p = W_hh0 + (size_t)row * 64 + kt * 32 + quad * 8;
            short8 a;
            #pragma unroll
            for (int j = 0; j < 8; ++j) a[j] = (short)f2bf(p[j]);
            afrag[i][kt] = a;
        }
    }

    // activation constants for cell (b=w, u=l)
    float wih0g[4], bias0g[4];
    #pragma unroll
    for (int g = 0; g < 4; ++g) {
        int r = g * 64 + l;
        wih0g[g] = W_ih0[r];
        bias0g[g] = b_ih0[r] + b_hh0[r];
    }
    // layer-2 constants
    float w1[4], whh1[4], b1s[4];
    #pragma unroll
    for (int g = 0; g < 4; ++g) {
        w1[g] = W_ih1[g * 64 + l];
        whh1[g] = W_hh1[g];
        b1s[g] = b_ih1[g] + b_hh1[g];
    }

    float c0 = 0.0f, h1 = 0.0f, c1 = 0.0f, xbuf = 0.0f;
    float c0n_prev = 0.0f;
    const float* inrow = input + (size_t)(bbase + w) * T_STEPS;
    float* outrow = out + (size_t)(bbase + w) * T_STEPS;

    __syncthreads();

    #pragma unroll 1
    for (int t = 0; t < T_STEPS; ++t) {
        if ((t & 63) == 0) xbuf = inrow[t + l];   // refill 64 steps of x

        // ---- phase A: MFMA for G(t) from h(t-1) ----
        // B-frag lane l, tile kt: units 32kt+8*quad+0..7 of batch n16
        short8 bf0 = *reinterpret_cast<const short8*>(&Hb[n16][4 * quad]);
        short8 bf1 = *reinterpret_cast<const short8*>(&Hb[n16][16 + 4 * quad]);
        #pragma unroll
        for (int i = 0; i < 4; ++i) {
            f32x4 z = {0.0f, 0.0f, 0.0f, 0.0f};
            z = __builtin_amdgcn_mfma_f32_16x16x32_bf16(afrag[i][0], bf0, z, 0, 0, 0);
            z = __builtin_amdgcn_mfma_f32_16x16x32_bf16(afrag[i][1], bf1, z, 0, 0, 0);
            const int m0 = 16 * (4 * w + i) + 4 * quad;   // C: col=lane&15, row=m0+reg
            *reinterpret_cast<f32x4*>(&G[n16][m0]) = z;
        }

        // ---- layer-2 cell for step t-1, in the MFMA shadow ----
        if (t > 0) {
            float s0 = wave_allsum(w1[0] * c0n_prev);
            float s1 = wave_allsum(w1[1] * c0n_prev);
            float s2 = wave_allsum(w1[2] * c0n_prev);
            float s3 = wave_allsum(w1[3] * c0n_prev);
            float g1i = s0 + b1s[0] + h1 * whh1[0];
            float g1f = s1 + b1s[1] + h1 * whh1[1];
            float g1g = s2 + b1s[2] + h1 * whh1[2];
            float g1o = s3 + b1s[3] + h1 * whh1[3];
            float c1n = sigf(g1f) * c1 + sigf(g1i) * tanh_fast(g1g);
            float h1n = sigf(g1o) * tanh_fast(c1n);
            c1 = c1n;
            h1 = h1n;
            if (l == 0) outrow[t - 1] = c1n;
        }
        __syncthreads();

        // ---- phase B: activation for cell (b=w, u=l) ----
        const float x = rl(xbuf, t & 63);
        float gi = G[w][l]       + fmaf(x, wih0g[0], bias0g[0]);
        float gf = G[w][64 + l]  + fmaf(x, wih0g[1], bias0g[1]);
        float gg = G[w][128 + l] + fmaf(x, wih0g[2], bias0g[2]);
        float go = G[w][192 + l] + fmaf(x, wih0g[3], bias0g[3]);

        float c0n = sigf(gf) * c0 + sigf(gi) * tanh_fast(gg);
        c0 = c0n;
        c0n_prev = c0n;
        float h0n = sigf(go) * tanh_fast(c0n);

        // pack (unit l, unit l+1) bf16 pair; even lanes write one b32:
        // banks (4w + l/2) mod 32 -> conflict-free
        unsigned own = f2bf(h0n);
        unsigned nb = dpp_shl1(own);
        if (!(l & 1)) Hb[w][l >> 1] = own | (nb << 16);

        __syncthreads();   // h(t) visible before next MFMA reads
    }

    // epilogue: layer-2 for the last step
    {
        float s0 = wave_allsum(w1[0] * c0n_prev);
        float s1 = wave_allsum(w1[1] * c0n_prev);
        float s2 = wave_allsum(w1[2] * c0n_prev);
        float s3 = wave_allsum(w1[3] * c0n_prev);
        float g1i = s0 + b1s[0] + h1 * whh1[0];
        float g1f = s1 + b1s[1] + h1 * whh1[1];
        float g1g = s2 + b1s[2] + h1 * whh1[2];
        float g1o = s3 + b1s[3] + h1 * whh1[3];
        float c1n = sigf(g1f) * c1 + sigf(g1i) * tanh_fast(g1g);
        if (l == 0) outrow[T_STEPS - 1] = c1n;
    }
}

extern "C" void kernel_launch(void* const* d_in, const int* in_sizes, int n_in,
                              void* d_out, int out_size, void* d_ws, size_t ws_size,
                              hipStream_t stream) {
    const float* input = (const float*)d_in[0];
    const float* W_ih0 = (const float*)d_in[1];
    const float* W_hh0 = (const float*)d_in[2];
    const float* b_ih0 = (const float*)d_in[3];
    const float* b_hh0 = (const float*)d_in[4];
    const float* W_ih1 = (const float*)d_in[5];
    const float* W_hh1 = (const float*)d_in[6];
    const float* b_ih1 = (const float*)d_in[7];
    const float* b_hh1 = (const float*)d_in[8];
    float* out = (float*)d_out;

    dim3 grid(BATCH / BTILE);   // 512 blocks -> 2 blocks/CU
    dim3 block(256);
    lstm_mfma2_kernel<<<grid, block, 0, stream>>>(
        input, W_ih0, W_hh0, b_ih0, b_hh0, W_ih1, W_hh1, b_ih1, b_hh1, out);
}